// Round 1
// baseline (1305.723 us; speedup 1.0000x reference)
//
#include <hip/hip_runtime.h>

// SupervisedGraphSage scatter kernel for MI355X (gfx950) — R3.
//
// out[c] = 1.0 iff ANY edge of clause c fires; firing test folded to
// score > 0.5*edge_feature (ef in {-1,+1}). Racing stores of identical
// 1.0f are benign — no atomics.
//
// R3 change: row-per-thread, shuffle-free. R2's 16-lane shuffle-reduce
// structure (20 LDS-pipe ops / 16 edges, lgkmcnt waits on the critical
// path, lane<16 divergent epilogue) held the scatter at ~1.65 TB/s
// (~640 us) — in-flight bytes/CU ~2.4 KB by Little's law, i.e. waves
// serialized on the shuffle-wait chain, not on HBM.
// Now: each thread owns one edge row (64 floats = 16 float4 loads,
// 256 B/lane in flight, 4x R2's MLP), weights forced to SGPRs, no
// cross-lane ops, no divergence except the final predicated store.
// Every 64B line is fully consumed by the issuing wave (lane i uses
// line (i,j/4) across 4 consecutive j) -> no HBM over-fetch.

__global__ __launch_bounds__(256) void zero_out(float4* __restrict__ out4, int n4) {
    int i = blockIdx.x * blockDim.x + threadIdx.x;
    if (i < n4) out4[i] = make_float4(0.f, 0.f, 0.f, 0.f);
}

__device__ __forceinline__ float uniform_f(float x) {
    // Force a wave-uniform value into an SGPR so FMA uses the scalar operand.
    union { float f; int i; } u;
    u.f = x;
    u.i = __builtin_amdgcn_readfirstlane(u.i);
    return u.f;
}

__global__ __launch_bounds__(256) void graphsage_row_per_thread(
    const float4* __restrict__ embeds4,      // [n_edges * 16]
    const float*  __restrict__ weight,       // [64]
    const float*  __restrict__ edge_feature, // [n_edges]
    const int*    __restrict__ edge_clause,  // [n_edges]
    float*        __restrict__ out,          // [n_clauses], pre-zeroed
    int n_edges)
{
    // Weights: uniform across lanes -> pin to SGPRs (64 SGPRs, budget ok).
    float w[64];
#pragma unroll
    for (int j = 0; j < 16; ++j) {
        float4 t = ((const float4*)weight)[j];
        w[4*j+0] = uniform_f(t.x);
        w[4*j+1] = uniform_f(t.y);
        w[4*j+2] = uniform_f(t.z);
        w[4*j+3] = uniform_f(t.w);
    }

    const int tid      = blockIdx.x * blockDim.x + threadIdx.x;
    const int nthreads = gridDim.x * blockDim.x;

    for (int e = tid; e < n_edges; e += nthreads) {
        const float4* __restrict__ row = embeds4 + (size_t)e * 16;

        // 16 independent dwordx4 loads in flight (256 B/lane).
        float4 v[16];
#pragma unroll
        for (int j = 0; j < 16; ++j) v[j] = row[j];

        // Coalesced per-edge metadata (all 64 lanes active).
        const float ef = edge_feature[e];
        const int   cl = edge_clause[e];

        // 4 partial accumulators for FMA ILP, combined at the end.
        float s0 = 0.f, s1 = 0.f, s2 = 0.f, s3 = 0.f;
#pragma unroll
        for (int j = 0; j < 16; j += 4) {
            s0 += v[j+0].x*w[4*j+0]  + v[j+0].y*w[4*j+1]  + v[j+0].z*w[4*j+2]  + v[j+0].w*w[4*j+3];
            s1 += v[j+1].x*w[4*j+4]  + v[j+1].y*w[4*j+5]  + v[j+1].z*w[4*j+6]  + v[j+1].w*w[4*j+7];
            s2 += v[j+2].x*w[4*j+8]  + v[j+2].y*w[4*j+9]  + v[j+2].z*w[4*j+10] + v[j+2].w*w[4*j+11];
            s3 += v[j+3].x*w[4*j+12] + v[j+3].y*w[4*j+13] + v[j+3].z*w[4*j+14] + v[j+3].w*w[4*j+15];
        }
        const float s = (s0 + s1) + (s2 + s3);

        // s + (1-ef)*0.5 > 0.5  <=>  s > 0.5*ef   (ef in {-1,+1})
        if (s > 0.5f * ef) out[cl] = 1.0f;   // benign race: same value
    }
}

extern "C" void kernel_launch(void* const* d_in, const int* in_sizes, int n_in,
                              void* d_out, int out_size, void* d_ws, size_t ws_size,
                              hipStream_t stream) {
    const float* embeds       = (const float*)d_in[0];  // [4M, 64]
    const float* weight       = (const float*)d_in[1];  // [64, 1]
    const float* edge_feature = (const float*)d_in[2];  // [4M, 1]
    const int*   edge_clause  = (const int*)d_in[3];    // [4M]

    float* out = (float*)d_out;
    const int n_edges = in_sizes[3];

    // Zero the output (harness poisons it with 0xAA before every launch).
    const int n4 = out_size / 4;   // out_size = 1M floats -> divisible by 4
    zero_out<<<(n4 + 255) / 256, 256, 0, stream>>>((float4*)out, n4);

    // 2048 blocks x 256 thr = 512K threads; ~8 grid-stride iterations over
    // 4M edges; each wave covers a contiguous 16 KB slab of embeds.
    const int block = 256;
    const int grid  = 2048;
    graphsage_row_per_thread<<<grid, block, 0, stream>>>(
        (const float4*)embeds, weight, edge_feature, edge_clause, out, n_edges);
}